// Round 4
// baseline (383.004 us; speedup 1.0000x reference)
//
#include <hip/hip_runtime.h>
#include <stdint.h>

typedef unsigned short u16;
typedef __attribute__((ext_vector_type(4))) float f32x4;
typedef __attribute__((ext_vector_type(8))) __bf16 bf16x8;

__device__ __forceinline__ float b2f(u16 u) {
  union { unsigned int i; float f; } v; v.i = ((unsigned int)u) << 16; return v.f;
}
__device__ __forceinline__ u16 f2b(float f) {
  union { float f; unsigned int i; } v; v.f = f;
  unsigned int x = v.i;
  return (u16)((x + 0x7fffu + ((x >> 16) & 1u)) >> 16);
}

__device__ __forceinline__ void async_ld16(const u16* g, u16* l) {
  __builtin_amdgcn_global_load_lds((const __attribute__((address_space(1))) void*)g,
                                   (__attribute__((address_space(3))) void*)l, 16, 0, 0);
}

// Counted-vmcnt pipeline sync: own loads for current tile done, next tile in flight.
__device__ __forceinline__ void pipe_wait4() {
  asm volatile("s_waitcnt vmcnt(4)" ::: "memory");
  __builtin_amdgcn_s_barrier();
  asm volatile("" ::: "memory");
}
__device__ __forceinline__ void pipe_wait0() {
  asm volatile("s_waitcnt vmcnt(0)" ::: "memory");
  __builtin_amdgcn_s_barrier();
  asm volatile("" ::: "memory");
}

// ---- dtype detection: flag=1 if inputs are f32, 0 if bf16 ------------------
__global__ void detect_kernel(const u16* __restrict__ x, int* __restrict__ flag)
{
  const int tid = threadIdx.x;
  int found = 0;
  for (int i = tid; i < 32768; i += 256) {
    u16 u = x[i];
    if ((u & 0x7F80u) == 0x7F80u) found = 1;
  }
  unsigned long long m = __ballot(found != 0);
  __shared__ int sf[4];
  if ((tid & 63) == 0) sf[tid >> 6] = (m != 0ULL) ? 1 : 0;
  __syncthreads();
  if (tid == 0) flag[0] = (sf[0] | sf[1] | sf[2] | sf[3]);
}

__global__ __launch_bounds__(256)
void conv_kernel(const void* __restrict__ in, u16* __restrict__ out, long n,
                 const int* __restrict__ flag)
{
  const long i = ((long)blockIdx.x * 256 + threadIdx.x) * 8;
  if (i >= n) return;
  if (flag[0]) {
    const float* p = (const float*)in + i;
    u16 o[8];
#pragma unroll
    for (int j = 0; j < 8; j++) o[j] = f2b(p[j]);
    *(uint4*)(out + i) = *(const uint4*)o;
  } else {
    *(uint4*)(out + i) = *(const uint4*)((const u16*)in + i);
  }
}

// 4 weight tensors (D*D=262144 elems each), 128 blocks per tensor.
__global__ __launch_bounds__(256)
void conv4_kernel(const void* __restrict__ i0, const void* __restrict__ i1,
                  const void* __restrict__ i2, const void* __restrict__ i3,
                  u16* __restrict__ o0, u16* __restrict__ o1,
                  u16* __restrict__ o2, u16* __restrict__ o3,
                  const int* __restrict__ flag)
{
  const int sel = blockIdx.x >> 7;
  const int blk = blockIdx.x & 127;
  const void* in = (sel == 0) ? i0 : (sel == 1) ? i1 : (sel == 2) ? i2 : i3;
  u16* out = (sel == 0) ? o0 : (sel == 1) ? o1 : (sel == 2) ? o2 : o3;
  const long i = ((long)blk * 256 + threadIdx.x) * 8;
  if (flag[0]) {
    const float* p = (const float*)in + i;
    u16 o[8];
#pragma unroll
    for (int j = 0; j < 8; j++) o[j] = f2b(p[j]);
    *(uint4*)(out + i) = *(const uint4*)o;
  } else {
    *(uint4*)(out + i) = *(const uint4*)((const u16*)in + i);
  }
}

#define BM 128
#define BN 128
#define BK 32

// Generic BT GEMM, 3-deep LDS pipeline with counted vmcnt (never drains in-loop).
// XCD swizzle: group all n-tiles of one A-row-panel on one XCD (consecutive).
// LDS swizzle: source-col XOR (lc^((lr>>1)&3)) + read-slot XOR (quad^((ll>>1)&3)).
template<int EPI>
__global__ __launch_bounds__(256)
void gemm_bt(const u16* __restrict__ A, const u16* __restrict__ B,
             const void* __restrict__ bias, void* __restrict__ Cv,
             const int* __restrict__ flag,
             int M, int N, int K, long strideC)
{
  __shared__ __align__(16) u16 sA[3][BM * BK];
  __shared__ __align__(16) u16 sB[3][BN * BK];

  const int tid  = threadIdx.x;
  const int lane = tid & 63;
  const int wv   = tid >> 6;
  const int fl = flag[0];
  u16* Cb16 = (u16*)Cv;

  int bx = blockIdx.x, by = blockIdx.y;
  {
    const int nx = gridDim.x, ny = gridDim.y;
    if ((nx & 7) == 0) {
      const int d   = bx + nx * by;
      const int xcd = d & 7;
      const int s   = d >> 3;
      const int q   = s / ny;
      bx = xcd * (nx >> 3) + q;
      by = s - q * ny;
    }
  }
  const int m0 = bx * BM;
  const int n0 = by * BN;

  const int ldRow = wv * 32;
  const int lr = lane >> 2;
  const int lc = lane & 3;
  const int scol = (lc ^ ((lr >> 1) & 3)) * 8;   // pre-swizzled global slot
  const u16* gA = A + (long)(m0 + ldRow + lr) * K + scol;
  const u16* gB = B + (long)(n0 + ldRow + lr) * K + scol;
  const int off0 = (ldRow + lr) * BK + lc * 8;
  const int off1 = (ldRow + 16 + lr) * BK + lc * 8;

  f32x4 acc[4][4];
#pragma unroll
  for (int i = 0; i < 4; i++)
#pragma unroll
    for (int j = 0; j < 4; j++) acc[i][j] = (f32x4)0.0f;

  const int waveM = (wv >> 1) * 64;
  const int waveN = (wv & 1) * 64;
  const int quad  = lane >> 4;
  const int ll    = lane & 15;
  const int rs    = (quad ^ ((ll >> 1) & 3)) * 8; // swizzled read slot

  // prologue: stage tiles 0 and 1
  async_ld16(gA,          sA[0] + off0);
  async_ld16(gA + 16 * K, sA[0] + off1);
  async_ld16(gB,          sB[0] + off0);
  async_ld16(gB + 16 * K, sB[0] + off1);
  gA += BK; gB += BK;
  async_ld16(gA,          sA[1] + off0);
  async_ld16(gA + 16 * K, sA[1] + off1);
  async_ld16(gB,          sB[1] + off0);
  async_ld16(gB + 16 * K, sB[1] + off1);
  gA += BK; gB += BK;

  const int NT = K / BK;
  int cur = 0;
  for (int t = 0; t < NT; ++t) {
    if (t < NT - 1) pipe_wait4(); else pipe_wait0();
    if (t + 2 < NT) {
      int pre = cur + 2; if (pre >= 3) pre -= 3;
      u16* dA = sA[pre];
      u16* dB = sB[pre];
      async_ld16(gA,          dA + off0);
      async_ld16(gA + 16 * K, dA + off1);
      async_ld16(gB,          dB + off0);
      async_ld16(gB + 16 * K, dB + off1);
      gA += BK; gB += BK;
    }
    const u16* rA = sA[cur];
    const u16* rB = sB[cur];
    bf16x8 aF[4], bF[4];
#pragma unroll
    for (int i = 0; i < 4; i++) {
      aF[i] = *(const bf16x8*)(rA + (waveM + i * 16 + ll) * BK + rs);
      bF[i] = *(const bf16x8*)(rB + (waveN + i * 16 + ll) * BK + rs);
    }
#pragma unroll
    for (int i = 0; i < 4; i++)
#pragma unroll
      for (int j = 0; j < 4; j++)
        acc[i][j] = __builtin_amdgcn_mfma_f32_16x16x32_bf16(aF[i], bF[j], acc[i][j], 0, 0, 0);
    cur += 1; if (cur == 3) cur = 0;
  }

#pragma unroll
  for (int i = 0; i < 4; i++) {
    const int rowb = m0 + waveM + i * 16 + quad * 4;
#pragma unroll
    for (int j = 0; j < 4; j++) {
      const int col = n0 + waveN + j * 16 + ll;
      const float bv = fl ? ((const float*)bias)[col] : b2f(((const u16*)bias)[col]);
#pragma unroll
      for (int r = 0; r < 4; r++) {
        const long idx = (long)(rowb + r) * N + col;
        const float v = acc[i][j][r] + bv;
        if (EPI == 0) {
          Cb16[idx] = f2b(v);
        } else {
          const long g = strideC + idx;
          if (fl) ((float*)Cv)[g] = v;
          else    ((u16*)Cv)[g]   = f2b(v);
        }
      }
    }
  }
}

// Fused K/V/Q projection: A = x [M, 512], B = Wpack [1536, 512] (Wk;Wv;Wq rows),
// cols [0,512)->K, [512,1024)->V, [1024,1536)->Q, each [M, 512] bf16 + bias.
__global__ __launch_bounds__(256)
void gemm_proj3(const u16* __restrict__ A, const u16* __restrict__ Bw,
                const void* __restrict__ kb, const void* __restrict__ vb,
                const void* __restrict__ qb,
                u16* __restrict__ Kp, u16* __restrict__ Vp, u16* __restrict__ Qp,
                const int* __restrict__ flag, int M)
{
  const int KD = 512;
  __shared__ __align__(16) u16 sA[3][BM * BK];
  __shared__ __align__(16) u16 sB[3][BN * BK];

  const int tid  = threadIdx.x;
  const int lane = tid & 63;
  const int wv   = tid >> 6;
  const int fl = flag[0];

  int bx = blockIdx.x, by = blockIdx.y;
  {
    const int nx = gridDim.x, ny = gridDim.y;
    if ((nx & 7) == 0) {
      const int d   = bx + nx * by;
      const int xcd = d & 7;
      const int s   = d >> 3;
      const int q   = s / ny;
      bx = xcd * (nx >> 3) + q;
      by = s - q * ny;
    }
  }
  const int m0 = bx * BM;
  const int n0 = by * BN;

  const int ldRow = wv * 32;
  const int lr = lane >> 2;
  const int lc = lane & 3;
  const int scol = (lc ^ ((lr >> 1) & 3)) * 8;
  const u16* gA = A  + (long)(m0 + ldRow + lr) * KD + scol;
  const u16* gB = Bw + (long)(n0 + ldRow + lr) * KD + scol;
  const int off0 = (ldRow + lr) * BK + lc * 8;
  const int off1 = (ldRow + 16 + lr) * BK + lc * 8;

  f32x4 acc[4][4];
#pragma unroll
  for (int i = 0; i < 4; i++)
#pragma unroll
    for (int j = 0; j < 4; j++) acc[i][j] = (f32x4)0.0f;

  const int waveM = (wv >> 1) * 64;
  const int waveN = (wv & 1) * 64;
  const int quad  = lane >> 4;
  const int ll    = lane & 15;
  const int rs    = (quad ^ ((ll >> 1) & 3)) * 8;

  async_ld16(gA,           sA[0] + off0);
  async_ld16(gA + 16 * KD, sA[0] + off1);
  async_ld16(gB,           sB[0] + off0);
  async_ld16(gB + 16 * KD, sB[0] + off1);
  gA += BK; gB += BK;
  async_ld16(gA,           sA[1] + off0);
  async_ld16(gA + 16 * KD, sA[1] + off1);
  async_ld16(gB,           sB[1] + off0);
  async_ld16(gB + 16 * KD, sB[1] + off1);
  gA += BK; gB += BK;

  const int NT = KD / BK;
  int cur = 0;
  for (int t = 0; t < NT; ++t) {
    if (t < NT - 1) pipe_wait4(); else pipe_wait0();
    if (t + 2 < NT) {
      int pre = cur + 2; if (pre >= 3) pre -= 3;
      u16* dA = sA[pre];
      u16* dB = sB[pre];
      async_ld16(gA,           dA + off0);
      async_ld16(gA + 16 * KD, dA + off1);
      async_ld16(gB,           dB + off0);
      async_ld16(gB + 16 * KD, dB + off1);
      gA += BK; gB += BK;
    }
    const u16* rA = sA[cur];
    const u16* rB = sB[cur];
    bf16x8 aF[4], bF[4];
#pragma unroll
    for (int i = 0; i < 4; i++) {
      aF[i] = *(const bf16x8*)(rA + (waveM + i * 16 + ll) * BK + rs);
      bF[i] = *(const bf16x8*)(rB + (waveN + i * 16 + ll) * BK + rs);
    }
#pragma unroll
    for (int i = 0; i < 4; i++)
#pragma unroll
      for (int j = 0; j < 4; j++)
        acc[i][j] = __builtin_amdgcn_mfma_f32_16x16x32_bf16(aF[i], bF[j], acc[i][j], 0, 0, 0);
    cur += 1; if (cur == 3) cur = 0;
  }

#pragma unroll
  for (int i = 0; i < 4; i++) {
    const int rowb = m0 + waveM + i * 16 + quad * 4;
#pragma unroll
    for (int j = 0; j < 4; j++) {
      const int col = n0 + waveN + j * 16 + ll;   // [0,1536)
      const int sel = col >> 9;
      const int cs  = col & 511;
      const void* bp = (sel == 0) ? kb : (sel == 1) ? vb : qb;
      u16* dst = (sel == 0) ? Kp : (sel == 1) ? Vp : Qp;
      const float bv = fl ? ((const float*)bp)[cs] : b2f(((const u16*)bp)[cs]);
#pragma unroll
      for (int r = 0; r < 4; r++)
        dst[(long)(rowb + r) * 512 + cs] = f2b(acc[i][j][r] + bv);
    }
  }
}

// Dual GEMM: num = ew @ PVt^T, den = ew @ Pt^T ; Yt = sigmoid(Q)*num/den.
// Wave tile 64x32 (dual), 3-deep counted-vmcnt pipeline, XCD panel-grouping.
#define AM 128
#define AN 64
#define ABK 32

__global__ __launch_bounds__(256, 2)
void gemm_aft(const u16* __restrict__ ew, const u16* __restrict__ Pt,
              const u16* __restrict__ PVt, const u16* __restrict__ Q,
              u16* __restrict__ Yt)
{
  const int T = 1024, D = 512;
  __shared__ __align__(16) u16 sA[3][AM * ABK];   // 3x8KB
  __shared__ __align__(16) u16 sB[3][AN * ABK];   // 3x4KB
  __shared__ __align__(16) u16 sC[3][AN * ABK];   // 3x4KB

  const int tid  = threadIdx.x;
  const int lane = tid & 63;
  const int wv   = tid >> 6;

  // XCD panel-grouping swizzle. grid = (8, 8, nz); bijective for any nz.
  int xt = blockIdx.x, yt = blockIdx.y, zt = blockIdx.z;
  {
    const int nz = gridDim.z;
    const int d   = xt + (yt << 3) + (zt << 6);
    const int xcd = d & 7;
    const int s   = d >> 3;               // [0, 8*nz)
    const int panel = xcd * nz + (s >> 3);
    xt = s & 7;
    yt = panel & 7;
    zt = panel >> 3;
  }
  const int b = zt;

  const u16* Ptb  = Pt  + (long)b * D * T;
  const u16* PVtb = PVt + (long)b * D * T;
  const u16* Qb   = Q   + (long)b * T * D;
  u16*       Ytb  = Yt  + (long)b * T * D;

  const int m0 = xt * AM;
  const int n0 = yt * AN;

  const int ldRow = wv * 16;          // 16 rows per wave per staged chunk
  const int lr = lane >> 2;
  const int lc = lane & 3;
  const int scol = (lc ^ ((lr >> 1) & 3)) * 8;   // pre-swizzled global slot
  const u16* gA = ew   + (long)(m0 + ldRow + lr) * T + scol;
  const u16* gB = Ptb  + (long)(n0 + ldRow + lr) * T + scol;
  const u16* gC = PVtb + (long)(n0 + ldRow + lr) * T + scol;
  const int offA0 = (ldRow + lr) * ABK + lc * 8;
  const int offA1 = (64 + ldRow + lr) * ABK + lc * 8;
  const int offB0 = (ldRow + lr) * ABK + lc * 8;

  f32x4 accN[4][2], accD[4][2];
#pragma unroll
  for (int i = 0; i < 4; i++)
#pragma unroll
    for (int j = 0; j < 2; j++) { accN[i][j] = (f32x4)0.0f; accD[i][j] = (f32x4)0.0f; }

  const int waveM = (wv >> 1) * 64;   // 2x2 wave grid: 64 rows x 32 cols per wave
  const int waveN = (wv & 1) * 32;
  const int quad  = lane >> 4;
  const int ll    = lane & 15;
  const int rs    = (quad ^ ((ll >> 1) & 3)) * 8; // swizzled read slot

  // prologue: stage tiles 0 and 1
  async_ld16(gA,          sA[0] + offA0);
  async_ld16(gA + 64 * T, sA[0] + offA1);
  async_ld16(gB,          sB[0] + offB0);
  async_ld16(gC,          sC[0] + offB0);
  gA += ABK; gB += ABK; gC += ABK;
  async_ld16(gA,          sA[1] + offA0);
  async_ld16(gA + 64 * T, sA[1] + offA1);
  async_ld16(gB,          sB[1] + offB0);
  async_ld16(gC,          sC[1] + offB0);
  gA += ABK; gB += ABK; gC += ABK;

  const int NT = T / ABK;
  int cur = 0;
  for (int t = 0; t < NT; ++t) {
    if (t < NT - 1) pipe_wait4(); else pipe_wait0();
    if (t + 2 < NT) {
      int pre = cur + 2; if (pre >= 3) pre -= 3;
      u16* dA = sA[pre];
      u16* dB = sB[pre];
      u16* dC = sC[pre];
      async_ld16(gA,          dA + offA0);
      async_ld16(gA + 64 * T, dA + offA1);
      async_ld16(gB,          dB + offB0);
      async_ld16(gC,          dC + offB0);
      gA += ABK; gB += ABK; gC += ABK;
    }
    const u16* rA = sA[cur];
    const u16* rB = sB[cur];
    const u16* rC = sC[cur];
    bf16x8 aF[4], bF[2], cF[2];
#pragma unroll
    for (int i = 0; i < 4; i++)
      aF[i] = *(const bf16x8*)(rA + (waveM + i * 16 + ll) * ABK + rs);
#pragma unroll
    for (int j = 0; j < 2; j++) {
      bF[j] = *(const bf16x8*)(rB + (waveN + j * 16 + ll) * ABK + rs);
      cF[j] = *(const bf16x8*)(rC + (waveN + j * 16 + ll) * ABK + rs);
    }
#pragma unroll
    for (int i = 0; i < 4; i++)
#pragma unroll
      for (int j = 0; j < 2; j++) {
        accD[i][j] = __builtin_amdgcn_mfma_f32_16x16x32_bf16(aF[i], bF[j], accD[i][j], 0, 0, 0);
        accN[i][j] = __builtin_amdgcn_mfma_f32_16x16x32_bf16(aF[i], cF[j], accN[i][j], 0, 0, 0);
      }
    cur += 1; if (cur == 3) cur = 0;
  }

#pragma unroll
  for (int i = 0; i < 4; i++) {
    const int rowb = m0 + waveM + i * 16 + quad * 4;
#pragma unroll
    for (int j = 0; j < 2; j++) {
      const int col = n0 + waveN + j * 16 + ll;
#pragma unroll
      for (int r = 0; r < 4; r++) {
        const long idx = (long)(rowb + r) * D + col;
        const float q  = b2f(Qb[idx]);
        // sigmoid(q)*num/den = num * rcp(den*(1+exp(-q)))  -- one v_rcp_f32
        const float t  = __expf(-q);
        const float rc = __builtin_amdgcn_rcpf(accD[i][j][r] * (1.0f + t));
        Ytb[idx] = f2b(accN[i][j][r] * rc);
      }
    }
  }
}

__global__ __launch_bounds__(256)
void expw_kernel(const void* __restrict__ w, u16* __restrict__ ew,
                 const int* __restrict__ flag)
{
  const int fl = flag[0];
  const int t = blockIdx.x;
  const int tid = threadIdx.x;
  float v[4];
  float m = -1e30f;
#pragma unroll
  for (int i = 0; i < 4; i++) {
    const long idx = (long)t * 1024 + tid + i * 256;
    float val = fl ? ((const float*)w)[idx] : b2f(((const u16*)w)[idx]);
    v[i] = val; m = fmaxf(m, val);
  }
#pragma unroll
  for (int off = 32; off > 0; off >>= 1) m = fmaxf(m, __shfl_xor(m, off, 64));
  __shared__ float sm[4];
  if ((tid & 63) == 0) sm[tid >> 6] = m;
  __syncthreads();
  m = fmaxf(fmaxf(sm[0], sm[1]), fmaxf(sm[2], sm[3]));
  u16* orow = ew + (long)t * 1024;
#pragma unroll
  for (int i = 0; i < 4; i++) orow[tid + i * 256] = f2b(__expf(v[i] - m));
}

__global__ __launch_bounds__(256)
void kmax_kernel(const u16* __restrict__ K, u16* __restrict__ Km)
{
  const long TD = 1024L * 512;
  const long base = ((long)blockIdx.x * 256 + threadIdx.x) * 8;
  float m[8];
#pragma unroll
  for (int j = 0; j < 8; j++) m[j] = -1e30f;
  for (int b = 0; b < 32; b++) {
    uint4 u = *(const uint4*)(K + b * TD + base);
    const u16* p = (const u16*)&u;
#pragma unroll
    for (int j = 0; j < 8; j++) m[j] = fmaxf(m[j], b2f(p[j]));
  }
  u16 outv[8];
#pragma unroll
  for (int j = 0; j < 8; j++) outv[j] = f2b(m[j]);
  *(uint4*)(Km + base) = *(const uint4*)outv;
}

__global__ __launch_bounds__(256)
void pexp_kernel(const u16* __restrict__ K, const u16* __restrict__ V,
                 const u16* __restrict__ Km,
                 u16* __restrict__ Pt, u16* __restrict__ PVt)
{
  const int T = 1024, D = 512;
  const long TD = (long)T * D;
  const int s0 = blockIdx.x * 64;
  const int d0 = blockIdx.y * 64;
  const int b  = blockIdx.z;
  __shared__ u16 lp[64 * 66];
  __shared__ u16 lpv[64 * 66];
  const int tid  = threadIdx.x;
  const int srow = tid >> 3;
  const int c8   = (tid & 7) * 8;

#pragma unroll
  for (int h = 0; h < 2; h++) {
    const int s = srow + h * 32;
    const long gidx = (long)b * TD + (long)(s0 + s) * D + d0 + c8;
    uint4 ku = *(const uint4*)(K + gidx);
    uint4 vu = *(const uint4*)(V + gidx);
    uint4 mu = *(const uint4*)(Km + (long)(s0 + s) * D + d0 + c8);
    const u16* kp = (const u16*)&ku;
    const u16* vp = (const u16*)&vu;
    const u16* mp = (const u16*)&mu;
#pragma unroll
    for (int j = 0; j < 8; j++) {
      float p  = __expf(b2f(kp[j]) - b2f(mp[j]));
      float pv = p * b2f(vp[j]);
      lp[s * 66 + c8 + j]  = f2b(p);
      lpv[s * 66 + c8 + j] = f2b(pv);
    }
  }
  __syncthreads();

  const int lane = tid & 63;
  const int wv   = tid >> 6;
#pragma unroll
  for (int it = 0; it < 16; it++) {
    const int d = wv * 16 + it;
    const long oidx = (long)b * TD + (long)(d0 + d) * T + s0 + lane;
    Pt[oidx]  = lp[lane * 66 + d];
    PVt[oidx] = lpv[lane * 66 + d];
  }
}

extern "C" void kernel_launch(void* const* d_in, const int* in_sizes, int n_in,
                              void* d_out, int out_size, void* d_ws, size_t ws_size,
                              hipStream_t stream)
{
  const int B = 32, T = 1024, D = 512;
  const long TD = (long)T * D;
  const void* x    = d_in[0];
  const void* Wk_w = d_in[1];
  const void* Wk_b = d_in[2];
  const void* Wv_w = d_in[3];
  const void* Wv_b = d_in[4];
  const void* Wq_w = d_in[5];
  const void* Wq_b = d_in[6];
  const void* w    = d_in[7];
  const void* Wo_w = d_in[8];
  const void* Wo_b = d_in[9];

  char* ws = (char*)d_ws;
  const size_t MB = 1024 * 1024;
  u16* xb    = (u16*)(ws + 0);          // 32MB [B*T, D]
  u16* Kbuf  = (u16*)(ws + 32 * MB);    // 32MB (aliased as Yt after pexp)
  u16* ewb   = (u16*)(ws + 64 * MB);    // 2MB
  u16* kmb   = (u16*)(ws + 66 * MB);    // 1MB
  u16* Wpack = (u16*)(ws + 67 * MB);    // 1.5MB: Wk;Wv;Wq rows [1536, 512]
  u16* Wvb   = Wpack + 512 * 512;
  u16* Wqb   = Wpack + 2 * 512 * 512;
  u16* Wob   = (u16*)(ws + 68 * MB + 512 * 1024); // 0.5MB
  int* flag  = (int*)(ws + 69 * MB);
  u16* Ytb   = Kbuf;

  dim3 blk(256);

  detect_kernel<<<dim3(1), blk, 0, stream>>>((const u16*)x, flag);
  conv_kernel<<<dim3(8192), blk, 0, stream>>>(x, xb, (long)B * T * D, flag);
  conv4_kernel<<<dim3(512), blk, 0, stream>>>(Wk_w, Wv_w, Wq_w, Wo_w,
                                              Wpack, Wvb, Wqb, Wob, flag);
  expw_kernel<<<dim3(1024), blk, 0, stream>>>(w, ewb, flag);

  if (ws_size >= 200 * MB) {
    // ---- full-batch single-pass path ----
    u16* Vb   = (u16*)(ws + 70 * MB);   // 32MB
    u16* Qb   = (u16*)(ws + 102 * MB);  // 32MB
    u16* Ptb  = (u16*)(ws + 134 * MB);  // 32MB
    u16* PVtb = (u16*)(ws + 166 * MB);  // 32MB -> ends 198MB

    // K,V,Q in one GEMM: N = 1536
    gemm_proj3<<<dim3((B * T) / 128, 12), blk, 0, stream>>>(
        xb, Wpack, Wk_b, Wv_b, Wq_b, Kbuf, Vb, Qb, flag, B * T);

    kmax_kernel<<<dim3(256), blk, 0, stream>>>(Kbuf, kmb);
    pexp_kernel<<<dim3(16, 8, 32), blk, 0, stream>>>(Kbuf, Vb, kmb, Ptb, PVtb);

    // Yt aliases Kbuf (dead after pexp)
    gemm_aft<<<dim3(T / AM, D / AN, 32), blk, 0, stream>>>(ewb, Ptb, PVtb, Qb, Ytb);

    gemm_bt<3><<<dim3((B * T) / 128, D / 128), blk, 0, stream>>>(
        Ytb, Wob, Wo_b, d_out, flag, B * T, D, D, 0);
  } else {
    // ---- chunked fallback (NB=4), R5 structure ----
    const int NB = 4, NC = B / NB;
    char* ck = ws + 70 * MB;
    const size_t cb = (size_t)NB * TD * sizeof(u16);
    u16* Vc   = (u16*)(ck);
    u16* Ptc  = (u16*)(ck + cb);
    u16* PVtc = (u16*)(ck + 2 * cb);
    u16* Qc   = (u16*)(ck + 3 * cb);
    u16* Ytc  = Vc;

    gemm_bt<0><<<dim3((B * T) / 128, D / 128), blk, 0, stream>>>(
        xb, Wpack, Wk_b, Kbuf, flag, B * T, D, D, 0);
    kmax_kernel<<<dim3(256), blk, 0, stream>>>(Kbuf, kmb);

    dim3 gP((NB * T) / 128, D / 128, 1);
    dim3 gA(T / AM, D / AN, NB);
    for (int c = 0; c < NC; c++) {
      const long off = (long)c * NB * TD;
      gemm_bt<0><<<gP, blk, 0, stream>>>(xb + off, Wvb, Wv_b, Vc, flag, NB * T, D, D, 0);
      gemm_bt<0><<<gP, blk, 0, stream>>>(xb + off, Wqb, Wq_b, Qc, flag, NB * T, D, D, 0);
      pexp_kernel<<<dim3(16, 8, NB), blk, 0, stream>>>(Kbuf + off, Vc, kmb, Ptc, PVtc);
      gemm_aft<<<gA, blk, 0, stream>>>(ewb, Ptc, PVtc, Qc, Ytc);
      gemm_bt<3><<<gP, blk, 0, stream>>>(Ytc, Wob, Wo_b, d_out, flag, NB * T, D, D, off);
    }
  }
}

// Round 5
// 378.185 us; speedup vs baseline: 1.0127x; 1.0127x over previous
//
#include <hip/hip_runtime.h>
#include <stdint.h>

typedef unsigned short u16;
typedef __attribute__((ext_vector_type(4))) float f32x4;
typedef __attribute__((ext_vector_type(8))) __bf16 bf16x8;

__device__ __forceinline__ float b2f(u16 u) {
  union { unsigned int i; float f; } v; v.i = ((unsigned int)u) << 16; return v.f;
}
__device__ __forceinline__ u16 f2b(float f) {
  union { float f; unsigned int i; } v; v.f = f;
  unsigned int x = v.i;
  return (u16)((x + 0x7fffu + ((x >> 16) & 1u)) >> 16);
}

__device__ __forceinline__ void async_ld16(const u16* g, u16* l) {
  __builtin_amdgcn_global_load_lds((const __attribute__((address_space(1))) void*)g,
                                   (__attribute__((address_space(3))) void*)l, 16, 0, 0);
}

// ---- dtype detection: flag=1 if inputs are f32, 0 if bf16 ------------------
__global__ void detect_kernel(const u16* __restrict__ x, int* __restrict__ flag)
{
  const int tid = threadIdx.x;
  int found = 0;
  for (int i = tid; i < 32768; i += 256) {
    u16 u = x[i];
    if ((u & 0x7F80u) == 0x7F80u) found = 1;
  }
  unsigned long long m = __ballot(found != 0);
  __shared__ int sf[4];
  if ((tid & 63) == 0) sf[tid >> 6] = (m != 0ULL) ? 1 : 0;
  __syncthreads();
  if (tid == 0) flag[0] = (sf[0] | sf[1] | sf[2] | sf[3]);
}

__global__ __launch_bounds__(256)
void conv_kernel(const void* __restrict__ in, u16* __restrict__ out, long n,
                 const int* __restrict__ flag)
{
  const long i = ((long)blockIdx.x * 256 + threadIdx.x) * 8;
  if (i >= n) return;
  if (flag[0]) {
    const float* p = (const float*)in + i;
    u16 o[8];
#pragma unroll
    for (int j = 0; j < 8; j++) o[j] = f2b(p[j]);
    *(uint4*)(out + i) = *(const uint4*)o;
  } else {
    *(uint4*)(out + i) = *(const uint4*)((const u16*)in + i);
  }
}

// 4 weight tensors (D*D=262144 elems each), 128 blocks per tensor.
__global__ __launch_bounds__(256)
void conv4_kernel(const void* __restrict__ i0, const void* __restrict__ i1,
                  const void* __restrict__ i2, const void* __restrict__ i3,
                  u16* __restrict__ o0, u16* __restrict__ o1,
                  u16* __restrict__ o2, u16* __restrict__ o3,
                  const int* __restrict__ flag)
{
  const int sel = blockIdx.x >> 7;
  const int blk = blockIdx.x & 127;
  const void* in = (sel == 0) ? i0 : (sel == 1) ? i1 : (sel == 2) ? i2 : i3;
  u16* out = (sel == 0) ? o0 : (sel == 1) ? o1 : (sel == 2) ? o2 : o3;
  const long i = ((long)blk * 256 + threadIdx.x) * 8;
  if (flag[0]) {
    const float* p = (const float*)in + i;
    u16 o[8];
#pragma unroll
    for (int j = 0; j < 8; j++) o[j] = f2b(p[j]);
    *(uint4*)(out + i) = *(const uint4*)o;
  } else {
    *(uint4*)(out + i) = *(const uint4*)((const u16*)in + i);
  }
}

#define BM 128
#define BN 128
#define BK 32

// Generic BT GEMM, double-buffered LDS (1 barrier / K-step). (R2 known-good)
template<int EPI>
__global__ __launch_bounds__(256)
void gemm_bt(const u16* __restrict__ A, const u16* __restrict__ B,
             const void* __restrict__ bias, void* __restrict__ Cv,
             const int* __restrict__ flag,
             int M, int N, int K, long strideC)
{
  __shared__ __align__(16) u16 sA[2][BM * BK];
  __shared__ __align__(16) u16 sB[2][BN * BK];

  const int tid  = threadIdx.x;
  const int lane = tid & 63;
  const int wv   = tid >> 6;
  const int fl = flag[0];
  u16* Cb16 = (u16*)Cv;

  int bx = blockIdx.x, by = blockIdx.y;
  {
    const int nx = gridDim.x, ny = gridDim.y;
    if ((nx & 7) == 0) {
      const int d   = bx + nx * by;
      const int xcd = d & 7;
      const int s   = d >> 3;
      const int q   = s / ny;
      bx = xcd * (nx >> 3) + q;
      by = s - q * ny;
    }
  }
  const int m0 = bx * BM;
  const int n0 = by * BN;

  const int ldRow = wv * 32;
  const int lr = lane >> 2;
  const int lc = lane & 3;
  const int scol = (lc ^ ((lr >> 1) & 3)) * 8;
  const u16* gA = A + (long)(m0 + ldRow + lr) * K + scol;
  const u16* gB = B + (long)(n0 + ldRow + lr) * K + scol;
  const int off0 = (ldRow + lr) * BK + lc * 8;
  const int off1 = (ldRow + 16 + lr) * BK + lc * 8;

  f32x4 acc[4][4];
#pragma unroll
  for (int i = 0; i < 4; i++)
#pragma unroll
    for (int j = 0; j < 4; j++) acc[i][j] = (f32x4)0.0f;

  const int waveM = (wv >> 1) * 64;
  const int waveN = (wv & 1) * 64;
  const int quad  = lane >> 4;
  const int ll    = lane & 15;
  const int rs    = (quad ^ ((ll >> 1) & 3)) * 8;

  async_ld16(gA,          sA[0] + off0);
  async_ld16(gA + 16 * K, sA[0] + off1);
  async_ld16(gB,          sB[0] + off0);
  async_ld16(gB + 16 * K, sB[0] + off1);
  gA += BK; gB += BK;

  const int NT = K / BK;
  for (int t = 0; t < NT; ++t) {
    __syncthreads();
    const int cur = t & 1;
    if (t + 1 < NT) {
      u16* dA = sA[cur ^ 1];
      u16* dB = sB[cur ^ 1];
      async_ld16(gA,          dA + off0);
      async_ld16(gA + 16 * K, dA + off1);
      async_ld16(gB,          dB + off0);
      async_ld16(gB + 16 * K, dB + off1);
      gA += BK; gB += BK;
    }
    const u16* rA = sA[cur];
    const u16* rB = sB[cur];
    bf16x8 aF[4], bF[4];
#pragma unroll
    for (int i = 0; i < 4; i++) {
      aF[i] = *(const bf16x8*)(rA + (waveM + i * 16 + ll) * BK + rs);
      bF[i] = *(const bf16x8*)(rB + (waveN + i * 16 + ll) * BK + rs);
    }
#pragma unroll
    for (int i = 0; i < 4; i++)
#pragma unroll
      for (int j = 0; j < 4; j++)
        acc[i][j] = __builtin_amdgcn_mfma_f32_16x16x32_bf16(aF[i], bF[j], acc[i][j], 0, 0, 0);
  }

#pragma unroll
  for (int i = 0; i < 4; i++) {
    const int rowb = m0 + waveM + i * 16 + quad * 4;
#pragma unroll
    for (int j = 0; j < 4; j++) {
      const int col = n0 + waveN + j * 16 + ll;
      const float bv = fl ? ((const float*)bias)[col] : b2f(((const u16*)bias)[col]);
#pragma unroll
      for (int r = 0; r < 4; r++) {
        const long idx = (long)(rowb + r) * N + col;
        const float v = acc[i][j][r] + bv;
        if (EPI == 0) {
          Cb16[idx] = f2b(v);
        } else {
          const long g = strideC + idx;
          if (fl) ((float*)Cv)[g] = v;
          else    ((u16*)Cv)[g]   = f2b(v);
        }
      }
    }
  }
}

// Fused K/V/Q projection (R2 known-good dbuf form).
__global__ __launch_bounds__(256)
void gemm_proj3(const u16* __restrict__ A, const u16* __restrict__ Bw,
                const void* __restrict__ kb, const void* __restrict__ vb,
                const void* __restrict__ qb,
                u16* __restrict__ Kp, u16* __restrict__ Vp, u16* __restrict__ Qp,
                const int* __restrict__ flag, int M)
{
  const int KD = 512;
  __shared__ __align__(16) u16 sA[2][BM * BK];
  __shared__ __align__(16) u16 sB[2][BN * BK];

  const int tid  = threadIdx.x;
  const int lane = tid & 63;
  const int wv   = tid >> 6;
  const int fl = flag[0];

  int bx = blockIdx.x, by = blockIdx.y;
  {
    const int nx = gridDim.x, ny = gridDim.y;
    if ((nx & 7) == 0) {
      const int d   = bx + nx * by;
      const int xcd = d & 7;
      const int s   = d >> 3;
      const int q   = s / ny;
      bx = xcd * (nx >> 3) + q;
      by = s - q * ny;
    }
  }
  const int m0 = bx * BM;
  const int n0 = by * BN;

  const int ldRow = wv * 32;
  const int lr = lane >> 2;
  const int lc = lane & 3;
  const int scol = (lc ^ ((lr >> 1) & 3)) * 8;
  const u16* gA = A  + (long)(m0 + ldRow + lr) * KD + scol;
  const u16* gB = Bw + (long)(n0 + ldRow + lr) * KD + scol;
  const int off0 = (ldRow + lr) * BK + lc * 8;
  const int off1 = (ldRow + 16 + lr) * BK + lc * 8;

  f32x4 acc[4][4];
#pragma unroll
  for (int i = 0; i < 4; i++)
#pragma unroll
    for (int j = 0; j < 4; j++) acc[i][j] = (f32x4)0.0f;

  const int waveM = (wv >> 1) * 64;
  const int waveN = (wv & 1) * 64;
  const int quad  = lane >> 4;
  const int ll    = lane & 15;
  const int rs    = (quad ^ ((ll >> 1) & 3)) * 8;

  async_ld16(gA,           sA[0] + off0);
  async_ld16(gA + 16 * KD, sA[0] + off1);
  async_ld16(gB,           sB[0] + off0);
  async_ld16(gB + 16 * KD, sB[0] + off1);
  gA += BK; gB += BK;

  const int NT = KD / BK;
  for (int t = 0; t < NT; ++t) {
    __syncthreads();
    const int cur = t & 1;
    if (t + 1 < NT) {
      u16* dA = sA[cur ^ 1];
      u16* dB = sB[cur ^ 1];
      async_ld16(gA,           dA + off0);
      async_ld16(gA + 16 * KD, dA + off1);
      async_ld16(gB,           dB + off0);
      async_ld16(gB + 16 * KD, dB + off1);
      gA += BK; gB += BK;
    }
    const u16* rA = sA[cur];
    const u16* rB = sB[cur];
    bf16x8 aF[4], bF[4];
#pragma unroll
    for (int i = 0; i < 4; i++) {
      aF[i] = *(const bf16x8*)(rA + (waveM + i * 16 + ll) * BK + rs);
      bF[i] = *(const bf16x8*)(rB + (waveN + i * 16 + ll) * BK + rs);
    }
#pragma unroll
    for (int i = 0; i < 4; i++)
#pragma unroll
      for (int j = 0; j < 4; j++)
        acc[i][j] = __builtin_amdgcn_mfma_f32_16x16x32_bf16(aF[i], bF[j], acc[i][j], 0, 0, 0);
  }

#pragma unroll
  for (int i = 0; i < 4; i++) {
    const int rowb = m0 + waveM + i * 16 + quad * 4;
#pragma unroll
    for (int j = 0; j < 4; j++) {
      const int col = n0 + waveN + j * 16 + ll;   // [0,1536)
      const int sel = col >> 9;
      const int cs  = col & 511;
      const void* bp = (sel == 0) ? kb : (sel == 1) ? vb : qb;
      u16* dst = (sel == 0) ? Kp : (sel == 1) ? Vp : Qp;
      const float bv = fl ? ((const float*)bp)[cs] : b2f(((const u16*)bp)[cs]);
#pragma unroll
      for (int r = 0; r < 4; r++)
        dst[(long)(rowb + r) * 512 + cs] = f2b(acc[i][j][r] + bv);
    }
  }
}

// ---------------------------------------------------------------------------
// gemm_aft, 8-phase structure (T2+T3+T4+T5):
//   tile 256(T) x 128(D, dual num/den), BK=64, 512 threads = 8 waves (2M x 4N).
//   LDS [dbuf][khalf][rows][32] so global_load_lds dest is lane-linear while
//   phases consume per-k-half subtiles. 4 phases/K-tile:
//     P0: k0,i0-3 (+bF/cF k0)  P1: k0,i4-7  P2: k1,i0-3 (+bF/cF k1)  P3: k1,i4-7
//   each phase: {ds_read ; 2x gload_lds(t+1) ; bar ; lgkm0+SB0 ; prio1 ; 16 MFMA ; prio0 ; bar}
//   vmcnt(4) at end of P1 and P3 only (counted, never 0 in steady state).
// ---------------------------------------------------------------------------
__global__ __launch_bounds__(512, 2)
void gemm_aft(const u16* __restrict__ ew, const u16* __restrict__ Pt,
              const u16* __restrict__ PVt, const u16* __restrict__ Q,
              u16* __restrict__ Yt)
{
  const int T = 1024, D = 512;
  __shared__ __align__(16) u16 sA[2 * 2 * 256 * 32];  // 64KB
  __shared__ __align__(16) u16 sB[2 * 2 * 128 * 32];  // 32KB
  __shared__ __align__(16) u16 sC[2 * 2 * 128 * 32];  // 32KB

  const int tid  = threadIdx.x;
  const int lane = tid & 63;
  const int wv   = tid >> 6;            // 0..7

  // XCD panel-grouping swizzle for grid (4,4,nz), nz even.
  int xt = blockIdx.x, yt = blockIdx.y, zt = blockIdx.z;
  {
    const int nz = gridDim.z;
    if ((nz & 1) == 0) {
      const int d   = xt + (yt << 2) + (zt << 4);
      const int xcd = d & 7;
      const int s   = d >> 3;           // [0, 2nz)
      xt = s & 3;
      const int p = xcd * (nz >> 1) + (s >> 2);
      yt = p & 3;
      zt = p >> 2;
    }
  }
  const int b = zt;
  const u16* Ptb  = Pt  + (long)b * D * T;
  const u16* PVtb = PVt + (long)b * D * T;
  const u16* Qb   = Q   + (long)b * T * D;
  u16*       Ytb  = Yt  + (long)b * T * D;
  const int m0 = xt * 256;
  const int n0 = yt * 128;

  // staging map: thread -> (row sr in [0,128), slot ss in [0,4)); lane-linear LDS.
  const int sr = tid >> 2, ss = tid & 3;
  const int sslot = (ss ^ ((sr >> 1) & 3)) * 8;     // swizzled k-chunk in 32-col half
  const u16* gA0 = ew   + (long)(m0 + sr)       * T + sslot;
  const u16* gA1 = ew   + (long)(m0 + 128 + sr) * T + sslot;
  const u16* gB  = Ptb  + (long)(n0 + sr)       * T + sslot;
  const u16* gC  = PVtb + (long)(n0 + sr)       * T + sslot;
  const int soff = sr * 32 + ss * 8;                // u16 units

  f32x4 accN[8][2], accD[8][2];
#pragma unroll
  for (int i = 0; i < 8; i++)
#pragma unroll
    for (int j = 0; j < 2; j++) { accN[i][j] = (f32x4)0.0f; accD[i][j] = (f32x4)0.0f; }

  const int quad  = lane >> 4;
  const int ll    = lane & 15;
  const int rs    = (quad ^ ((ll >> 1) & 3)) * 8;
  const int waveM = (wv >> 2) * 128;
  const int waveN = (wv & 3) * 32;

  // prologue: stage tile 0 (k0 group then k1 group) into buf 0
  async_ld16(gA0,      sA + soff);
  async_ld16(gA1,      sA + 4096 + soff);
  async_ld16(gB,       sB + soff);
  async_ld16(gC,       sC + soff);
  async_ld16(gA0 + 32, sA + 8192 + soff);
  async_ld16(gA1 + 32, sA + 8192 + 4096 + soff);
  async_ld16(gB  + 32, sB + 4096 + soff);
  async_ld16(gC  + 32, sC + 4096 + soff);
  asm volatile("s_waitcnt vmcnt(4)" ::: "memory");
  __builtin_amdgcn_s_barrier();

  const int NT = T / 64;   // 16
  for (int t = 0; t < NT; ++t) {
    const int cur = t & 1;
    const u16* bA = sA + cur * 16384;
    const u16* bB = sB + cur * 8192;
    const u16* bC = sC + cur * 8192;
    u16* nA = sA + (cur ^ 1) * 16384;
    u16* nB = sB + (cur ^ 1) * 8192;
    u16* nC = sC + (cur ^ 1) * 8192;
    const int ko = (t + 1) * 64;
    const bool st = (t + 1 < NT);

    bf16x8 aF[4], bF[2], cF[2];

    // ---- P0: k0, i 0..3 (+ bF/cF k0) ----
#pragma unroll
    for (int i = 0; i < 4; i++)
      aF[i] = *(const bf16x8*)(bA + (waveM + i * 16 + ll) * 32 + rs);
#pragma unroll
    for (int j = 0; j < 2; j++) {
      bF[j] = *(const bf16x8*)(bB + (waveN + j * 16 + ll) * 32 + rs);
      cF[j] = *(const bf16x8*)(bC + (waveN + j * 16 + ll) * 32 + rs);
    }
    if (st) {
      async_ld16(gA0 + ko, nA + soff);
      async_ld16(gA1 + ko, nA + 4096 + soff);
    }
    __builtin_amdgcn_s_barrier();
    asm volatile("s_waitcnt lgkmcnt(0)" ::: "memory");
    __builtin_amdgcn_sched_barrier(0);
    __builtin_amdgcn_s_setprio(1);
#pragma unroll
    for (int i = 0; i < 4; i++)
#pragma unroll
      for (int j = 0; j < 2; j++) {
        accD[i][j] = __builtin_amdgcn_mfma_f32_16x16x32_bf16(aF[i], bF[j], accD[i][j], 0, 0, 0);
        accN[i][j] = __builtin_amdgcn_mfma_f32_16x16x32_bf16(aF[i], cF[j], accN[i][j], 0, 0, 0);
      }
    __builtin_amdgcn_s_setprio(0);
    __builtin_amdgcn_s_barrier();

    // ---- P1: k0, i 4..7 ----
#pragma unroll
    for (int i = 0; i < 4; i++)
      aF[i] = *(const bf16x8*)(bA + (waveM + (4 + i) * 16 + ll) * 32 + rs);
    if (st) {
      async_ld16(gB + ko, nB + soff);
      async_ld16(gC + ko, nC + soff);
    }
    __builtin_amdgcn_s_barrier();
    asm volatile("s_waitcnt lgkmcnt(0)" ::: "memory");
    __builtin_amdgcn_sched_barrier(0);
    __builtin_amdgcn_s_setprio(1);
#pragma unroll
    for (int i = 0; i < 4; i++)
#pragma unroll
      for (int j = 0; j < 2; j++) {
        accD[4 + i][j] = __builtin_amdgcn_mfma_f32_16x16x32_bf16(aF[i], bF[j], accD[4 + i][j], 0, 0, 0);
        accN[4 + i][j] = __builtin_amdgcn_mfma_f32_16x16x32_bf16(aF[i], cF[j], accN[4 + i][j], 0, 0, 0);
      }
    __builtin_amdgcn_s_setprio(0);
    if (st) asm volatile("s_waitcnt vmcnt(4)" ::: "memory");
    else    asm volatile("s_waitcnt vmcnt(0)" ::: "memory");
    __builtin_amdgcn_s_barrier();

    // ---- P2: k1, i 0..3 (+ bF/cF k1) ----
    const u16* bA1 = bA + 8192;
    const u16* bB1 = bB + 4096;
    const u16* bC1 = bC + 4096;
#pragma unroll
    for (int i = 0; i < 4; i++)
      aF[i] = *(const bf16x8*)(bA1 + (waveM + i * 16 + ll) * 32 + rs);
#pragma unroll
    for (int j = 0; j < 2; j++) {
      bF[j] = *(const bf16x8*)(bB1 + (waveN + j * 16 + ll) * 32 + rs);
      cF[j] = *(const bf16x8*)(bC1 + (waveN + j * 16 + ll) * 32 + rs);
    }
    if (st) {
      async_ld16(gA0 + ko + 32, nA + 8192 + soff);
      async_ld16(gA1 + ko + 32, nA + 8192 + 4096 + soff);
    }
    __builtin_amdgcn_s_barrier();
    asm volatile("s_waitcnt lgkmcnt(0)" ::: "memory");
    __builtin_amdgcn_sched_barrier(0);
    __builtin_amdgcn_s_setprio(1);
#pragma unroll
    for (int i = 0; i < 4; i++)
#pragma unroll
      for (int j = 0; j < 2; j++) {
        accD[i][j] = __builtin_amdgcn_mfma_f32_16x16x32_bf16(aF[i], bF[j], accD[i][j], 0, 0, 0);
        accN[i][j] = __builtin_amdgcn_mfma_f32_16x16x32_bf16(aF[i], cF[j], accN[i][j], 0, 0, 0);
      }
    __builtin_amdgcn_s_setprio(0);
    __builtin_amdgcn_s_barrier();

    // ---- P3: k1, i 4..7 ----
#pragma unroll
    for (int i = 0; i < 4; i++)
      aF[i] = *(const bf16x8*)(bA1 + (waveM + (4 + i) * 16 + ll) * 32 + rs);
    if (st) {
      async_ld16(gB + ko + 32, nB + 4096 + soff);
      async_ld16(gC + ko + 32, nC + 4096 + soff);
    }
    __builtin_amdgcn_s_barrier();
    asm volatile("s_waitcnt lgkmcnt(0)" ::: "memory");
    __builtin_amdgcn_sched_barrier(0);
    __builtin_amdgcn_s_setprio(1);
#pragma unroll
    for (int i = 0; i < 4; i++)
#pragma unroll
      for (int j = 0; j < 2; j++) {
        accD[4 + i][j] = __builtin_amdgcn_mfma_f32_16x16x32_bf16(aF[i], bF[j], accD[4 + i][j], 0, 0, 0);
        accN[4 + i][j] = __builtin_amdgcn_mfma_f32_16x16x32_bf16(aF[i], cF[j], accN[4 + i][j], 0, 0, 0);
      }
    __builtin_amdgcn_s_setprio(0);
    if (st) asm volatile("s_waitcnt vmcnt(4)" ::: "memory");
    else    asm volatile("s_waitcnt vmcnt(0)" ::: "memory");
    __builtin_amdgcn_s_barrier();
  }

#pragma unroll
  for (int i = 0; i < 8; i++) {
    const int rowb = m0 + waveM + i * 16 + quad * 4;
#pragma unroll
    for (int j = 0; j < 2; j++) {
      const int col = n0 + waveN + j * 16 + ll;
#pragma unroll
      for (int r = 0; r < 4; r++) {
        const long idx = (long)(rowb + r) * D + col;
        const float q  = b2f(Qb[idx]);
        const float e  = __expf(-q);
        const float rc = __builtin_amdgcn_rcpf(accD[i][j][r] * (1.0f + e));
        Ytb[idx] = f2b(accN[i][j][r] * rc);
      }
    }
  }
}

__global__ __launch_bounds__(256)
void expw_kernel(const void* __restrict__ w, u16* __restrict__ ew,
                 const int* __restrict__ flag)
{
  const int fl = flag[0];
  const int t = blockIdx.x;
  const int tid = threadIdx.x;
  float v[4];
  float m = -1e30f;
#pragma unroll
  for (int i = 0; i < 4; i++) {
    const long idx = (long)t * 1024 + tid + i * 256;
    float val = fl ? ((const float*)w)[idx] : b2f(((const u16*)w)[idx]);
    v[i] = val; m = fmaxf(m, val);
  }
#pragma unroll
  for (int off = 32; off > 0; off >>= 1) m = fmaxf(m, __shfl_xor(m, off, 64));
  __shared__ float sm[4];
  if ((tid & 63) == 0) sm[tid >> 6] = m;
  __syncthreads();
  m = fmaxf(fmaxf(sm[0], sm[1]), fmaxf(sm[2], sm[3]));
  u16* orow = ew + (long)t * 1024;
#pragma unroll
  for (int i = 0; i < 4; i++) orow[tid + i * 256] = f2b(__expf(v[i] - m));
}

__global__ __launch_bounds__(256)
void kmax_kernel(const u16* __restrict__ K, u16* __restrict__ Km)
{
  const long TD = 1024L * 512;
  const long base = ((long)blockIdx.x * 256 + threadIdx.x) * 8;
  float m[8];
#pragma unroll
  for (int j = 0; j < 8; j++) m[j] = -1e30f;
  for (int b = 0; b < 32; b++) {
    uint4 u = *(const uint4*)(K + b * TD + base);
    const u16* p = (const u16*)&u;
#pragma unroll
    for (int j = 0; j < 8; j++) m[j] = fmaxf(m[j], b2f(p[j]));
  }
  u16 outv[8];
#pragma unroll
  for (int j = 0; j < 8; j++) outv[j] = f2b(m[j]);
  *(uint4*)(Km + base) = *(const uint4*)outv;
}

__global__ __launch_bounds__(256)
void pexp_kernel(const u16* __restrict__ K, const u16* __restrict__ V,
                 const u16* __restrict__ Km,
                 u16* __restrict__ Pt, u16* __restrict__ PVt)
{
  const int T = 1024, D = 512;
  const long TD = (long)T * D;
  const int s0 = blockIdx.x * 64;
  const int d0 = blockIdx.y * 64;
  const int b  = blockIdx.z;
  __shared__ u16 lp[64 * 66];
  __shared__ u16 lpv[64 * 66];
  const int tid  = threadIdx.x;
  const int srow = tid >> 3;
  const int c8   = (tid & 7) * 8;

#pragma unroll
  for (int h = 0; h < 2; h++) {
    const int s = srow + h * 32;
    const long gidx = (long)b * TD + (long)(s0 + s) * D + d0 + c8;
    uint4 ku = *(const uint4*)(K + gidx);
    uint4 vu = *(const uint4*)(V + gidx);
    uint4 mu = *(const uint4*)(Km + (long)(s0 + s) * D + d0 + c8);
    const u16* kp = (const u16*)&ku;
    const u16* vp = (const u16*)&vu;
    const u16* mp = (const u16*)&mu;
#pragma unroll
    for (int j = 0; j < 8; j++) {
      float p  = __expf(b2f(kp[j]) - b2f(mp[j]));
      float pv = p * b2f(vp[j]);
      lp[s * 66 + c8 + j]  = f2b(p);
      lpv[s * 66 + c8 + j] = f2b(pv);
    }
  }
  __syncthreads();

  const int lane = tid & 63;
  const int wv   = tid >> 6;
#pragma unroll
  for (int it = 0; it < 16; it++) {
    const int d = wv * 16 + it;
    const long oidx = (long)b * TD + (long)(d0 + d) * T + s0 + lane;
    Pt[oidx]  = lp[lane * 66 + d];
    PVt[oidx] = lpv[lane * 66 + d];
  }
}

extern "C" void kernel_launch(void* const* d_in, const int* in_sizes, int n_in,
                              void* d_out, int out_size, void* d_ws, size_t ws_size,
                              hipStream_t stream)
{
  const int B = 32, T = 1024, D = 512;
  const long TD = (long)T * D;
  const void* x    = d_in[0];
  const void* Wk_w = d_in[1];
  const void* Wk_b = d_in[2];
  const void* Wv_w = d_in[3];
  const void* Wv_b = d_in[4];
  const void* Wq_w = d_in[5];
  const void* Wq_b = d_in[6];
  const void* w    = d_in[7];
  const void* Wo_w = d_in[8];
  const void* Wo_b = d_in[9];

  char* ws = (char*)d_ws;
  const size_t MB = 1024 * 1024;
  u16* xb    = (u16*)(ws + 0);          // 32MB [B*T, D]
  u16* Kbuf  = (u16*)(ws + 32 * MB);    // 32MB (aliased as Yt after pexp)
  u16* ewb   = (u16*)(ws + 64 * MB);    // 2MB
  u16* kmb   = (u16*)(ws + 66 * MB);    // 1MB
  u16* Wpack = (u16*)(ws + 67 * MB);    // 1.5MB: Wk;Wv;Wq rows [1536, 512]
  u16* Wvb   = Wpack + 512 * 512;
  u16* Wqb   = Wpack + 2 * 512 * 512;
  u16* Wob   = (u16*)(ws + 68 * MB + 512 * 1024); // 0.5MB
  int* flag  = (int*)(ws + 69 * MB);
  u16* Ytb   = Kbuf;

  dim3 blk(256);

  detect_kernel<<<dim3(1), blk, 0, stream>>>((const u16*)x, flag);
  conv_kernel<<<dim3(8192), blk, 0, stream>>>(x, xb, (long)B * T * D, flag);
  conv4_kernel<<<dim3(512), blk, 0, stream>>>(Wk_w, Wv_w, Wq_w, Wo_w,
                                              Wpack, Wvb, Wqb, Wob, flag);
  expw_kernel<<<dim3(1024), blk, 0, stream>>>(w, ewb, flag);

  if (ws_size >= 200 * MB) {
    // ---- full-batch single-pass path ----
    u16* Vb   = (u16*)(ws + 70 * MB);   // 32MB
    u16* Qb   = (u16*)(ws + 102 * MB);  // 32MB
    u16* Ptb  = (u16*)(ws + 134 * MB);  // 32MB
    u16* PVtb = (u16*)(ws + 166 * MB);  // 32MB -> ends 198MB

    // K,V,Q in one GEMM: N = 1536
    gemm_proj3<<<dim3((B * T) / 128, 12), blk, 0, stream>>>(
        xb, Wpack, Wk_b, Wv_b, Wq_b, Kbuf, Vb, Qb, flag, B * T);

    kmax_kernel<<<dim3(256), blk, 0, stream>>>(Kbuf, kmb);
    pexp_kernel<<<dim3(16, 8, 32), blk, 0, stream>>>(Kbuf, Vb, kmb, Ptb, PVtb);

    // Yt aliases Kbuf (dead after pexp)
    gemm_aft<<<dim3(4, 4, 32), dim3(512), 0, stream>>>(ewb, Ptb, PVtb, Qb, Ytb);

    gemm_bt<3><<<dim3((B * T) / 128, D / 128), blk, 0, stream>>>(
        Ytb, Wob, Wo_b, d_out, flag, B * T, D, D, 0);
  } else {
    // ---- chunked fallback (NB=4) ----
    const int NB = 4, NC = B / NB;
    char* ck = ws + 70 * MB;
    const size_t cb = (size_t)NB * TD * sizeof(u16);
    u16* Vc   = (u16*)(ck);
    u16* Ptc  = (u16*)(ck + cb);
    u16* PVtc = (u16*)(ck + 2 * cb);
    u16* Qc   = (u16*)(ck + 3 * cb);
    u16* Ytc  = Vc;

    gemm_bt<0><<<dim3((B * T) / 128, D / 128), blk, 0, stream>>>(
        xb, Wpack, Wk_b, Kbuf, flag, B * T, D, D, 0);
    kmax_kernel<<<dim3(256), blk, 0, stream>>>(Kbuf, kmb);

    dim3 gP((NB * T) / 128, D / 128, 1);
    dim3 gA(4, 4, NB);
    for (int c = 0; c < NC; c++) {
      const long off = (long)c * NB * TD;
      gemm_bt<0><<<gP, blk, 0, stream>>>(xb + off, Wvb, Wv_b, Vc, flag, NB * T, D, D, 0);
      gemm_bt<0><<<gP, blk, 0, stream>>>(xb + off, Wqb, Wq_b, Qc, flag, NB * T, D, D, 0);
      pexp_kernel<<<dim3(16, 8, NB), blk, 0, stream>>>(Kbuf + off, Vc, kmb, Ptc, PVtc);
      gemm_aft<<<gA, dim3(512), 0, stream>>>(ewb, Ptc, PVtc, Qc, Ytc);
      gemm_bt<3><<<gP, blk, 0, stream>>>(Ytc, Wob, Wo_b, d_out, flag, NB * T, D, D, off);
    }
  }
}

// Round 6
// 375.753 us; speedup vs baseline: 1.0193x; 1.0065x over previous
//
#include <hip/hip_runtime.h>
#include <stdint.h>

typedef unsigned short u16;
typedef __attribute__((ext_vector_type(4))) float f32x4;
typedef __attribute__((ext_vector_type(8))) __bf16 bf16x8;

__device__ __forceinline__ float b2f(u16 u) {
  union { unsigned int i; float f; } v; v.i = ((unsigned int)u) << 16; return v.f;
}
__device__ __forceinline__ u16 f2b(float f) {
  union { float f; unsigned int i; } v; v.f = f;
  unsigned int x = v.i;
  return (u16)((x + 0x7fffu + ((x >> 16) & 1u)) >> 16);
}

__device__ __forceinline__ void async_ld16(const u16* g, u16* l) {
  __builtin_amdgcn_global_load_lds((const __attribute__((address_space(1))) void*)g,
                                   (__attribute__((address_space(3))) void*)l, 16, 0, 0);
}

// ---- dtype detection: flag=1 if inputs are f32, 0 if bf16 ------------------
__global__ void detect_kernel(const u16* __restrict__ x, int* __restrict__ flag)
{
  const int tid = threadIdx.x;
  int found = 0;
  for (int i = tid; i < 32768; i += 256) {
    u16 u = x[i];
    if ((u & 0x7F80u) == 0x7F80u) found = 1;
  }
  unsigned long long m = __ballot(found != 0);
  __shared__ int sf[4];
  if ((tid & 63) == 0) sf[tid >> 6] = (m != 0ULL) ? 1 : 0;
  __syncthreads();
  if (tid == 0) flag[0] = (sf[0] | sf[1] | sf[2] | sf[3]);
}

__global__ __launch_bounds__(256)
void conv_kernel(const void* __restrict__ in, u16* __restrict__ out, long n,
                 const int* __restrict__ flag)
{
  const long i = ((long)blockIdx.x * 256 + threadIdx.x) * 8;
  if (i >= n) return;
  if (flag[0]) {
    const float* p = (const float*)in + i;
    u16 o[8];
#pragma unroll
    for (int j = 0; j < 8; j++) o[j] = f2b(p[j]);
    *(uint4*)(out + i) = *(const uint4*)o;
  } else {
    *(uint4*)(out + i) = *(const uint4*)((const u16*)in + i);
  }
}

// 4 weight tensors (D*D=262144 elems each), 128 blocks per tensor.
__global__ __launch_bounds__(256)
void conv4_kernel(const void* __restrict__ i0, const void* __restrict__ i1,
                  const void* __restrict__ i2, const void* __restrict__ i3,
                  u16* __restrict__ o0, u16* __restrict__ o1,
                  u16* __restrict__ o2, u16* __restrict__ o3,
                  const int* __restrict__ flag)
{
  const int sel = blockIdx.x >> 7;
  const int blk = blockIdx.x & 127;
  const void* in = (sel == 0) ? i0 : (sel == 1) ? i1 : (sel == 2) ? i2 : i3;
  u16* out = (sel == 0) ? o0 : (sel == 1) ? o1 : (sel == 2) ? o2 : o3;
  const long i = ((long)blk * 256 + threadIdx.x) * 8;
  if (flag[0]) {
    const float* p = (const float*)in + i;
    u16 o[8];
#pragma unroll
    for (int j = 0; j < 8; j++) o[j] = f2b(p[j]);
    *(uint4*)(out + i) = *(const uint4*)o;
  } else {
    *(uint4*)(out + i) = *(const uint4*)((const u16*)in + i);
  }
}

#define BM 128
#define BN 128
#define BK 32

// Generic BT GEMM, double-buffered LDS (R2 known-good) -- fallback path only.
template<int EPI>
__global__ __launch_bounds__(256)
void gemm_bt(const u16* __restrict__ A, const u16* __restrict__ B,
             const void* __restrict__ bias, void* __restrict__ Cv,
             const int* __restrict__ flag,
             int M, int N, int K, long strideC)
{
  __shared__ __align__(16) u16 sA[2][BM * BK];
  __shared__ __align__(16) u16 sB[2][BN * BK];

  const int tid  = threadIdx.x;
  const int lane = tid & 63;
  const int wv   = tid >> 6;
  const int fl = flag[0];
  u16* Cb16 = (u16*)Cv;

  int bx = blockIdx.x, by = blockIdx.y;
  {
    const int nx = gridDim.x, ny = gridDim.y;
    if ((nx & 7) == 0) {
      const int d   = bx + nx * by;
      const int xcd = d & 7;
      const int s   = d >> 3;
      const int q   = s / ny;
      bx = xcd * (nx >> 3) + q;
      by = s - q * ny;
    }
  }
  const int m0 = bx * BM;
  const int n0 = by * BN;

  const int ldRow = wv * 32;
  const int lr = lane >> 2;
  const int lc = lane & 3;
  const int scol = (lc ^ ((lr >> 1) & 3)) * 8;
  const u16* gA = A + (long)(m0 + ldRow + lr) * K + scol;
  const u16* gB = B + (long)(n0 + ldRow + lr) * K + scol;
  const int off0 = (ldRow + lr) * BK + lc * 8;
  const int off1 = (ldRow + 16 + lr) * BK + lc * 8;

  f32x4 acc[4][4];
#pragma unroll
  for (int i = 0; i < 4; i++)
#pragma unroll
    for (int j = 0; j < 4; j++) acc[i][j] = (f32x4)0.0f;

  const int waveM = (wv >> 1) * 64;
  const int waveN = (wv & 1) * 64;
  const int quad  = lane >> 4;
  const int ll    = lane & 15;
  const int rs    = (quad ^ ((ll >> 1) & 3)) * 8;

  async_ld16(gA,          sA[0] + off0);
  async_ld16(gA + 16 * K, sA[0] + off1);
  async_ld16(gB,          sB[0] + off0);
  async_ld16(gB + 16 * K, sB[0] + off1);
  gA += BK; gB += BK;

  const int NT = K / BK;
  for (int t = 0; t < NT; ++t) {
    __syncthreads();
    const int cur = t & 1;
    if (t + 1 < NT) {
      u16* dA = sA[cur ^ 1];
      u16* dB = sB[cur ^ 1];
      async_ld16(gA,          dA + off0);
      async_ld16(gA + 16 * K, dA + off1);
      async_ld16(gB,          dB + off0);
      async_ld16(gB + 16 * K, dB + off1);
      gA += BK; gB += BK;
    }
    const u16* rA = sA[cur];
    const u16* rB = sB[cur];
    bf16x8 aF[4], bF[4];
#pragma unroll
    for (int i = 0; i < 4; i++) {
      aF[i] = *(const bf16x8*)(rA + (waveM + i * 16 + ll) * BK + rs);
      bF[i] = *(const bf16x8*)(rB + (waveN + i * 16 + ll) * BK + rs);
    }
#pragma unroll
    for (int i = 0; i < 4; i++)
#pragma unroll
      for (int j = 0; j < 4; j++)
        acc[i][j] = __builtin_amdgcn_mfma_f32_16x16x32_bf16(aF[i], bF[j], acc[i][j], 0, 0, 0);
  }

#pragma unroll
  for (int i = 0; i < 4; i++) {
    const int rowb = m0 + waveM + i * 16 + quad * 4;
#pragma unroll
    for (int j = 0; j < 4; j++) {
      const int col = n0 + waveN + j * 16 + ll;
      const float bv = fl ? ((const float*)bias)[col] : b2f(((const u16*)bias)[col]);
#pragma unroll
      for (int r = 0; r < 4; r++) {
        const long idx = (long)(rowb + r) * N + col;
        const float v = acc[i][j][r] + bv;
        if (EPI == 0) {
          Cb16[idx] = f2b(v);
        } else {
          const long g = strideC + idx;
          if (fl) ((float*)Cv)[g] = v;
          else    ((u16*)Cv)[g]   = f2b(v);
        }
      }
    }
  }
}

// ---------------------------------------------------------------------------
// 8-phase 256x256 GEMM body (T2+T3+T4+T5), BK=64, 512 threads = 8 waves (2Mx4N),
// per-wave 128x64 output (acc[8][4]). LDS [dbuf][khalf][256][32] per operand
// (64KB each, 128KB total). 4 phases/K-tile; vmcnt(4) only at P1/P3 ends.
// Staging: thread -> row sr=tid>>2 (plus sr+128), swizzled slot ss^((sr>>1)&3).
// Same swizzle algebra as the harness-verified gemm_aft.
// ---------------------------------------------------------------------------
#define GEMM8_PHASES(KROW)                                                      \
  const int NT = (KROW) / 64;                                                   \
  for (int t = 0; t < NT; ++t) {                                                \
    const int cur = t & 1;                                                      \
    const u16* bA = sA + cur * 16384;                                           \
    const u16* bB = sB + cur * 16384;                                           \
    u16* nA = sA + (cur ^ 1) * 16384;                                           \
    u16* nB = sB + (cur ^ 1) * 16384;                                           \
    const int ko = (t + 1) * 64;                                                \
    const bool st = (t + 1 < NT);                                               \
    bf16x8 aF[4], bF[4];                                                        \
    /* P0: k0, i0-3 (+ bF k0) */                                                \
    _Pragma("unroll")                                                           \
    for (int i = 0; i < 4; i++)                                                 \
      aF[i] = *(const bf16x8*)(bA + (waveM + i * 16 + ll) * 32 + rs);           \
    _Pragma("unroll")                                                           \
    for (int j = 0; j < 4; j++)                                                 \
      bF[j] = *(const bf16x8*)(bB + (waveN + j * 16 + ll) * 32 + rs);           \
    if (st) {                                                                   \
      async_ld16(gA0 + ko, nA + soff);                                          \
      async_ld16(gA1 + ko, nA + 4096 + soff);                                   \
    }                                                                           \
    __builtin_amdgcn_s_barrier();                                               \
    asm volatile("s_waitcnt lgkmcnt(0)" ::: "memory");                          \
    __builtin_amdgcn_sched_barrier(0);                                          \
    __builtin_amdgcn_s_setprio(1);                                              \
    _Pragma("unroll")                                                           \
    for (int i = 0; i < 4; i++)                                                 \
      _Pragma("unroll")                                                         \
      for (int j = 0; j < 4; j++)                                               \
        acc[i][j] = __builtin_amdgcn_mfma_f32_16x16x32_bf16(aF[i], bF[j], acc[i][j], 0, 0, 0); \
    __builtin_amdgcn_s_setprio(0);                                              \
    __builtin_amdgcn_s_barrier();                                               \
    /* P1: k0, i4-7 */                                                          \
    _Pragma("unroll")                                                           \
    for (int i = 0; i < 4; i++)                                                 \
      aF[i] = *(const bf16x8*)(bA + (waveM + (4 + i) * 16 + ll) * 32 + rs);     \
    if (st) {                                                                   \
      async_ld16(gB0 + ko, nB + soff);                                          \
      async_ld16(gB1 + ko, nB + 4096 + soff);                                   \
    }                                                                           \
    __builtin_amdgcn_s_barrier();                                               \
    asm volatile("s_waitcnt lgkmcnt(0)" ::: "memory");                          \
    __builtin_amdgcn_sched_barrier(0);                                          \
    __builtin_amdgcn_s_setprio(1);                                              \
    _Pragma("unroll")                                                           \
    for (int i = 0; i < 4; i++)                                                 \
      _Pragma("unroll")                                                         \
      for (int j = 0; j < 4; j++)                                               \
        acc[4 + i][j] = __builtin_amdgcn_mfma_f32_16x16x32_bf16(aF[i], bF[j], acc[4 + i][j], 0, 0, 0); \
    __builtin_amdgcn_s_setprio(0);                                              \
    if (st) asm volatile("s_waitcnt vmcnt(4)" ::: "memory");                    \
    else    asm volatile("s_waitcnt vmcnt(0)" ::: "memory");                    \
    __builtin_amdgcn_s_barrier();                                               \
    /* P2: k1, i0-3 (+ bF k1) */                                                \
    const u16* bA1 = bA + 8192;                                                 \
    const u16* bB1 = bB + 8192;                                                 \
    _Pragma("unroll")                                                           \
    for (int i = 0; i < 4; i++)                                                 \
      aF[i] = *(const bf16x8*)(bA1 + (waveM + i * 16 + ll) * 32 + rs);          \
    _Pragma("unroll")                                                           \
    for (int j = 0; j < 4; j++)                                                 \
      bF[j] = *(const bf16x8*)(bB1 + (waveN + j * 16 + ll) * 32 + rs);          \
    if (st) {                                                                   \
      async_ld16(gA0 + ko + 32, nA + 8192 + soff);                              \
      async_ld16(gA1 + ko + 32, nA + 8192 + 4096 + soff);                       \
    }                                                                           \
    __builtin_amdgcn_s_barrier();                                               \
    asm volatile("s_waitcnt lgkmcnt(0)" ::: "memory");                          \
    __builtin_amdgcn_sched_barrier(0);                                          \
    __builtin_amdgcn_s_setprio(1);                                              \
    _Pragma("unroll")                                                           \
    for (int i = 0; i < 4; i++)                                                 \
      _Pragma("unroll")                                                         \
      for (int j = 0; j < 4; j++)                                               \
        acc[i][j] = __builtin_amdgcn_mfma_f32_16x16x32_bf16(aF[i], bF[j], acc[i][j], 0, 0, 0); \
    __builtin_amdgcn_s_setprio(0);                                              \
    __builtin_amdgcn_s_barrier();                                               \
    /* P3: k1, i4-7 */                                                          \
    _Pragma("unroll")                                                           \
    for (int i = 0; i < 4; i++)                                                 \
      aF[i] = *(const bf16x8*)(bA1 + (waveM + (4 + i) * 16 + ll) * 32 + rs);    \
    if (st) {                                                                   \
      async_ld16(gB0 + ko + 32, nB + 8192 + soff);                              \
      async_ld16(gB1 + ko + 32, nB + 8192 + 4096 + soff);                       \
    }                                                                           \
    __builtin_amdgcn_s_barrier();                                               \
    asm volatile("s_waitcnt lgkmcnt(0)" ::: "memory");                          \
    __builtin_amdgcn_sched_barrier(0);                                          \
    __builtin_amdgcn_s_setprio(1);                                              \
    _Pragma("unroll")                                                           \
    for (int i = 0; i < 4; i++)                                                 \
      _Pragma("unroll")                                                         \
      for (int j = 0; j < 4; j++)                                               \
        acc[4 + i][j] = __builtin_amdgcn_mfma_f32_16x16x32_bf16(aF[i], bF[j], acc[4 + i][j], 0, 0, 0); \
    __builtin_amdgcn_s_setprio(0);                                              \
    if (st) asm volatile("s_waitcnt vmcnt(4)" ::: "memory");                    \
    else    asm volatile("s_waitcnt vmcnt(0)" ::: "memory");                    \
    __builtin_amdgcn_s_barrier();                                               \
  }

#define GEMM8_PRO(KROW)                                                         \
  async_ld16(gA0,      sA + soff);                                              \
  async_ld16(gA1,      sA + 4096 + soff);                                       \
  async_ld16(gB0,      sB + soff);                                              \
  async_ld16(gB1,      sB + 4096 + soff);                                       \
  async_ld16(gA0 + 32, sA + 8192 + soff);                                       \
  async_ld16(gA1 + 32, sA + 8192 + 4096 + soff);                                \
  async_ld16(gB0 + 32, sB + 8192 + soff);                                       \
  async_ld16(gB1 + 32, sB + 8192 + 4096 + soff);                                \
  asm volatile("s_waitcnt vmcnt(4)" ::: "memory");                              \
  __builtin_amdgcn_s_barrier();

// Fused K/V/Q projection, 8-phase. A = x [M,512], Bw = Wpack [1536,512].
__global__ __launch_bounds__(512, 2)
void gemm_proj3(const u16* __restrict__ A, const u16* __restrict__ Bw,
                const void* __restrict__ kb, const void* __restrict__ vb,
                const void* __restrict__ qb,
                u16* __restrict__ Kp, u16* __restrict__ Vp, u16* __restrict__ Qp,
                const int* __restrict__ flag, int M)
{
  const int KD = 512;
  __shared__ __align__(16) u16 sA[2 * 2 * 256 * 32];  // 64KB
  __shared__ __align__(16) u16 sB[2 * 2 * 256 * 32];  // 64KB

  const int tid  = threadIdx.x;
  const int lane = tid & 63;
  const int wv   = tid >> 6;
  const int fl = flag[0];

  int bx = blockIdx.x, by = blockIdx.y;
  {
    const int nx = gridDim.x, ny = gridDim.y;   // (128, 6)
    const int d   = bx + nx * by;
    const int xcd = d & 7;
    const int s   = d >> 3;
    const int q   = s / ny;
    bx = xcd * (nx >> 3) + q;
    by = s - q * ny;
  }
  const int m0 = bx * 256;
  const int n0 = by * 256;

  const int sr = tid >> 2, ss = tid & 3;
  const int sslot = (ss ^ ((sr >> 1) & 3)) * 8;
  const u16* gA0 = A  + (long)(m0 + sr)       * KD + sslot;
  const u16* gA1 = A  + (long)(m0 + 128 + sr) * KD + sslot;
  const u16* gB0 = Bw + (long)(n0 + sr)       * KD + sslot;
  const u16* gB1 = Bw + (long)(n0 + 128 + sr) * KD + sslot;
  const int soff = sr * 32 + ss * 8;

  f32x4 acc[8][4];
#pragma unroll
  for (int i = 0; i < 8; i++)
#pragma unroll
    for (int j = 0; j < 4; j++) acc[i][j] = (f32x4)0.0f;

  const int quad  = lane >> 4;
  const int ll    = lane & 15;
  const int rs    = (quad ^ ((ll >> 1) & 3)) * 8;
  const int waveM = (wv >> 2) * 128;
  const int waveN = (wv & 3) * 64;

  GEMM8_PRO(KD)
  GEMM8_PHASES(KD)

#pragma unroll
  for (int i = 0; i < 8; i++) {
    const int rowb = m0 + waveM + i * 16 + quad * 4;
#pragma unroll
    for (int j = 0; j < 4; j++) {
      const int col = n0 + waveN + j * 16 + ll;   // [0,1536)
      const int sel = col >> 9;
      const int cs  = col & 511;
      const void* bp = (sel == 0) ? kb : (sel == 1) ? vb : qb;
      u16* dst = (sel == 0) ? Kp : (sel == 1) ? Vp : Qp;
      const float bv = fl ? ((const float*)bp)[cs] : b2f(((const u16*)bp)[cs]);
#pragma unroll
      for (int r = 0; r < 4; r++)
        dst[(long)(rowb + r) * 512 + cs] = f2b(acc[i][j][r] + bv);
    }
  }
}

// Output projection, 8-phase: C = A @ B^T + bias, flag-dtype store to d_out.
__global__ __launch_bounds__(512, 2)
void gemm_out8(const u16* __restrict__ A, const u16* __restrict__ Bw,
               const void* __restrict__ bias, void* __restrict__ Cv,
               const int* __restrict__ flag, int M, int N, int K)
{
  __shared__ __align__(16) u16 sA[2 * 2 * 256 * 32];  // 64KB
  __shared__ __align__(16) u16 sB[2 * 2 * 256 * 32];  // 64KB

  const int tid  = threadIdx.x;
  const int lane = tid & 63;
  const int wv   = tid >> 6;
  const int fl = flag[0];

  int bx = blockIdx.x, by = blockIdx.y;
  {
    const int nx = gridDim.x, ny = gridDim.y;   // (128, 2)
    const int d   = bx + nx * by;
    const int xcd = d & 7;
    const int s   = d >> 3;
    const int q   = s / ny;
    bx = xcd * (nx >> 3) + q;
    by = s - q * ny;
  }
  const int m0 = bx * 256;
  const int n0 = by * 256;

  const int sr = tid >> 2, ss = tid & 3;
  const int sslot = (ss ^ ((sr >> 1) & 3)) * 8;
  const u16* gA0 = A  + (long)(m0 + sr)       * K + sslot;
  const u16* gA1 = A  + (long)(m0 + 128 + sr) * K + sslot;
  const u16* gB0 = Bw + (long)(n0 + sr)       * K + sslot;
  const u16* gB1 = Bw + (long)(n0 + 128 + sr) * K + sslot;
  const int soff = sr * 32 + ss * 8;

  f32x4 acc[8][4];
#pragma unroll
  for (int i = 0; i < 8; i++)
#pragma unroll
    for (int j = 0; j < 4; j++) acc[i][j] = (f32x4)0.0f;

  const int quad  = lane >> 4;
  const int ll    = lane & 15;
  const int rs    = (quad ^ ((ll >> 1) & 3)) * 8;
  const int waveM = (wv >> 2) * 128;
  const int waveN = (wv & 3) * 64;

  GEMM8_PRO(K)
  GEMM8_PHASES(K)

#pragma unroll
  for (int i = 0; i < 8; i++) {
    const int rowb = m0 + waveM + i * 16 + quad * 4;
#pragma unroll
    for (int j = 0; j < 4; j++) {
      const int col = n0 + waveN + j * 16 + ll;
      const float bv = fl ? ((const float*)bias)[col] : b2f(((const u16*)bias)[col]);
#pragma unroll
      for (int r = 0; r < 4; r++) {
        const long idx = (long)(rowb + r) * N + col;
        const float v = acc[i][j][r] + bv;
        if (fl) ((float*)Cv)[idx] = v;
        else    ((u16*)Cv)[idx]   = f2b(v);
      }
    }
  }
}

// ---------------------------------------------------------------------------
// gemm_aft, 8-phase (harness-verified in R4) -- unchanged.
// ---------------------------------------------------------------------------
__global__ __launch_bounds__(512, 2)
void gemm_aft(const u16* __restrict__ ew, const u16* __restrict__ Pt,
              const u16* __restrict__ PVt, const u16* __restrict__ Q,
              u16* __restrict__ Yt)
{
  const int T = 1024, D = 512;
  __shared__ __align__(16) u16 sA[2 * 2 * 256 * 32];  // 64KB
  __shared__ __align__(16) u16 sB[2 * 2 * 128 * 32];  // 32KB
  __shared__ __align__(16) u16 sC[2 * 2 * 128 * 32];  // 32KB

  const int tid  = threadIdx.x;
  const int lane = tid & 63;
  const int wv   = tid >> 6;            // 0..7

  int xt = blockIdx.x, yt = blockIdx.y, zt = blockIdx.z;
  {
    const int nz = gridDim.z;
    if ((nz & 1) == 0) {
      const int d   = xt + (yt << 2) + (zt << 4);
      const int xcd = d & 7;
      const int s   = d >> 3;
      xt = s & 3;
      const int p = xcd * (nz >> 1) + (s >> 2);
      yt = p & 3;
      zt = p >> 2;
    }
  }
  const int b = zt;
  const u16* Ptb  = Pt  + (long)b * D * T;
  const u16* PVtb = PVt + (long)b * D * T;
  const u16* Qb   = Q   + (long)b * T * D;
  u16*       Ytb  = Yt  + (long)b * T * D;
  const int m0 = xt * 256;
  const int n0 = yt * 128;

  const int sr = tid >> 2, ss = tid & 3;
  const int sslot = (ss ^ ((sr >> 1) & 3)) * 8;
  const u16* gA0 = ew   + (long)(m0 + sr)       * T + sslot;
  const u16* gA1 = ew   + (long)(m0 + 128 + sr) * T + sslot;
  const u16* gB  = Ptb  + (long)(n0 + sr)       * T + sslot;
  const u16* gC  = PVtb + (long)(n0 + sr)       * T + sslot;
  const int soff = sr * 32 + ss * 8;

  f32x4 accN[8][2], accD[8][2];
#pragma unroll
  for (int i = 0; i < 8; i++)
#pragma unroll
    for (int j = 0; j < 2; j++) { accN[i][j] = (f32x4)0.0f; accD[i][j] = (f32x4)0.0f; }

  const int quad  = lane >> 4;
  const int ll    = lane & 15;
  const int rs    = (quad ^ ((ll >> 1) & 3)) * 8;
  const int waveM = (wv >> 2) * 128;
  const int waveN = (wv & 3) * 32;

  async_ld16(gA0,      sA + soff);
  async_ld16(gA1,      sA + 4096 + soff);
  async_ld16(gB,       sB + soff);
  async_ld16(gC,       sC + soff);
  async_ld16(gA0 + 32, sA + 8192 + soff);
  async_ld16(gA1 + 32, sA + 8192 + 4096 + soff);
  async_ld16(gB  + 32, sB + 4096 + soff);
  async_ld16(gC  + 32, sC + 4096 + soff);
  asm volatile("s_waitcnt vmcnt(4)" ::: "memory");
  __builtin_amdgcn_s_barrier();

  const int NT = T / 64;   // 16
  for (int t = 0; t < NT; ++t) {
    const int cur = t & 1;
    const u16* bA = sA + cur * 16384;
    const u16* bB = sB + cur * 8192;
    const u16* bC = sC + cur * 8192;
    u16* nA = sA + (cur ^ 1) * 16384;
    u16* nB = sB + (cur ^ 1) * 8192;
    u16* nC = sC + (cur ^ 1) * 8192;
    const int ko = (t + 1) * 64;
    const bool st = (t + 1 < NT);

    bf16x8 aF[4], bF[2], cF[2];

    // ---- P0 ----
#pragma unroll
    for (int i = 0; i < 4; i++)
      aF[i] = *(const bf16x8*)(bA + (waveM + i * 16 + ll) * 32 + rs);
#pragma unroll
    for (int j = 0; j < 2; j++) {
      bF[j] = *(const bf16x8*)(bB + (waveN + j * 16 + ll) * 32 + rs);
      cF[j] = *(const bf16x8*)(bC + (waveN + j * 16 + ll) * 32 + rs);
    }
    if (st) {
      async_ld16(gA0 + ko, nA + soff);
      async_ld16(gA1 + ko, nA + 4096 + soff);
    }
    __builtin_amdgcn_s_barrier();
    asm volatile("s_waitcnt lgkmcnt(0)" ::: "memory");
    __builtin_amdgcn_sched_barrier(0);
    __builtin_amdgcn_s_setprio(1);
#pragma unroll
    for (int i = 0; i < 4; i++)
#pragma unroll
      for (int j = 0; j < 2; j++) {
        accD[i][j] = __builtin_amdgcn_mfma_f32_16x16x32_bf16(aF[i], bF[j], accD[i][j], 0, 0, 0);
        accN[i][j] = __builtin_amdgcn_mfma_f32_16x16x32_bf16(aF[i], cF[j], accN[i][j], 0, 0, 0);
      }
    __builtin_amdgcn_s_setprio(0);
    __builtin_amdgcn_s_barrier();

    // ---- P1 ----
#pragma unroll
    for (int i = 0; i < 4; i++)
      aF[i] = *(const bf16x8*)(bA + (waveM + (4 + i) * 16 + ll) * 32 + rs);
    if (st) {
      async_ld16(gB + ko, nB + soff);
      async_ld16(gC + ko, nC + soff);
    }
    __builtin_amdgcn_s_barrier();
    asm volatile("s_waitcnt lgkmcnt(0)" ::: "memory");
    __builtin_amdgcn_sched_barrier(0);
    __builtin_amdgcn_s_setprio(1);
#pragma unroll
    for (int i = 0; i < 4; i++)
#pragma unroll
      for (int j = 0; j < 2; j++) {
        accD[4 + i][j] = __builtin_amdgcn_mfma_f32_16x16x32_bf16(aF[i], bF[j], accD[4 + i][j], 0, 0, 0);
        accN[4 + i][j] = __builtin_amdgcn_mfma_f32_16x16x32_bf16(aF[i], cF[j], accN[4 + i][j], 0, 0, 0);
      }
    __builtin_amdgcn_s_setprio(0);
    if (st) asm volatile("s_waitcnt vmcnt(4)" ::: "memory");
    else    asm volatile("s_waitcnt vmcnt(0)" ::: "memory");
    __builtin_amdgcn_s_barrier();

    // ---- P2 ----
    const u16* bA1 = bA + 8192;
    const u16* bB1 = bB + 4096;
    const u16* bC1 = bC + 4096;
#pragma unroll
    for (int i = 0; i < 4; i++)
      aF[i] = *(const bf16x8*)(bA1 + (waveM + i * 16 + ll) * 32 + rs);
#pragma unroll
    for (int j = 0; j < 2; j++) {
      bF[j] = *(const bf16x8*)(bB1 + (waveN + j * 16 + ll) * 32 + rs);
      cF[j] = *(const bf16x8*)(bC1 + (waveN + j * 16 + ll) * 32 + rs);
    }
    if (st) {
      async_ld16(gA0 + ko + 32, nA + 8192 + soff);
      async_ld16(gA1 + ko + 32, nA + 8192 + 4096 + soff);
    }
    __builtin_amdgcn_s_barrier();
    asm volatile("s_waitcnt lgkmcnt(0)" ::: "memory");
    __builtin_amdgcn_sched_barrier(0);
    __builtin_amdgcn_s_setprio(1);
#pragma unroll
    for (int i = 0; i < 4; i++)
#pragma unroll
      for (int j = 0; j < 2; j++) {
        accD[i][j] = __builtin_amdgcn_mfma_f32_16x16x32_bf16(aF[i], bF[j], accD[i][j], 0, 0, 0);
        accN[i][j] = __builtin_amdgcn_mfma_f32_16x16x32_bf16(aF[i], cF[j], accN[i][j], 0, 0, 0);
      }
    __builtin_amdgcn_s_setprio(0);
    __builtin_amdgcn_s_barrier();

    // ---- P3 ----
#pragma unroll
    for (int i = 0; i < 4; i++)
      aF[i] = *(const bf16x8*)(bA1 + (waveM + (4 + i) * 16 + ll) * 32 + rs);
    if (st) {
      async_ld16(gB + ko + 32, nB + 4096 + soff);
      async_ld16(gC + ko + 32, nC + 4096 + soff);
    }
    __builtin_amdgcn_s_barrier();
    asm volatile("s_waitcnt lgkmcnt(0)" ::: "memory");
    __builtin_amdgcn_sched_barrier(0);
    __builtin_amdgcn_s_setprio(1);
#pragma unroll
    for (int i = 0; i < 4; i++)
#pragma unroll
      for (int j = 0; j < 2; j++) {
        accD[4 + i][j] = __builtin_amdgcn_mfma_f32_16x16x32_bf16(aF[i], bF[j], accD[4 + i][j], 0, 0, 0);
        accN[4 + i][j] = __builtin_amdgcn_mfma_f32_16x16x32_bf16(aF[i], cF[j], accN[4 + i][j], 0, 0, 0);
      }
    __builtin_amdgcn_s_setprio(0);
    if (st) asm volatile("s_waitcnt vmcnt(4)" ::: "memory");
    else    asm volatile("s_waitcnt vmcnt(0)" ::: "memory");
    __builtin_amdgcn_s_barrier();
  }

#pragma unroll
  for (int i = 0; i < 8; i++) {
    const int rowb = m0 + waveM + i * 16 + quad * 4;
#pragma unroll
    for (int j = 0; j < 2; j++) {
      const int col = n0 + waveN + j * 16 + ll;
#pragma unroll
      for (int r = 0; r < 4; r++) {
        const long idx = (long)(rowb + r) * D + col;
        const float q  = b2f(Qb[idx]);
        const float e  = __expf(-q);
        const float rc = __builtin_amdgcn_rcpf(accD[i][j][r] * (1.0f + e));
        Ytb[idx] = f2b(accN[i][j][r] * rc);
      }
    }
  }
}

__global__ __launch_bounds__(256)
void expw_kernel(const void* __restrict__ w, u16* __restrict__ ew,
                 const int* __restrict__ flag)
{
  const int fl = flag[0];
  const int t = blockIdx.x;
  const int tid = threadIdx.x;
  float v[4];
  float m = -1e30f;
#pragma unroll
  for (int i = 0; i < 4; i++) {
    const long idx = (long)t * 1024 + tid + i * 256;
    float val = fl ? ((const float*)w)[idx] : b2f(((const u16*)w)[idx]);
    v[i] = val; m = fmaxf(m, val);
  }
#pragma unroll
  for (int off = 32; off > 0; off >>= 1) m = fmaxf(m, __shfl_xor(m, off, 64));
  __shared__ float sm[4];
  if ((tid & 63) == 0) sm[tid >> 6] = m;
  __syncthreads();
  m = fmaxf(fmaxf(sm[0], sm[1]), fmaxf(sm[2], sm[3]));
  u16* orow = ew + (long)t * 1024;
#pragma unroll
  for (int i = 0; i < 4; i++) orow[tid + i * 256] = f2b(__expf(v[i] - m));
}

__global__ __launch_bounds__(256)
void kmax_kernel(const u16* __restrict__ K, u16* __restrict__ Km)
{
  const long TD = 1024L * 512;
  const long base = ((long)blockIdx.x * 256 + threadIdx.x) * 8;
  float m[8];
#pragma unroll
  for (int j = 0; j < 8; j++) m[j] = -1e30f;
  for (int b = 0; b < 32; b++) {
    uint4 u = *(const uint4*)(K + b * TD + base);
    const u16* p = (const u16*)&u;
#pragma unroll
    for (int j = 0; j < 8; j++) m[j] = fmaxf(m[j], b2f(p[j]));
  }
  u16 outv[8];
#pragma unroll
  for (int j = 0; j < 8; j++) outv[j] = f2b(m[j]);
  *(uint4*)(Km + base) = *(const uint4*)outv;
}

__global__ __launch_bounds__(256)
void pexp_kernel(const u16* __restrict__ K, const u16* __restrict__ V,
                 const u16* __restrict__ Km,
                 u16* __restrict__ Pt, u16* __restrict__ PVt)
{
  const int T = 1024, D = 512;
  const long TD = (long)T * D;
  const int s0 = blockIdx.x * 64;
  const int d0 = blockIdx.y * 64;
  const int b  = blockIdx.z;
  __shared__ u16 lp[64 * 66];
  __shared__ u16 lpv[64 * 66];
  const int tid  = threadIdx.x;
  const int srow = tid >> 3;
  const int c8   = (tid & 7) * 8;

#pragma unroll
  for (int h = 0; h < 2; h++) {
    const int s = srow + h * 32;
    const long gidx = (long)b * TD + (long)(s0 + s) * D + d0 + c8;
    uint4 ku = *(const uint4*)(K + gidx);
    uint4 vu = *(const uint4*)(V + gidx);
    uint4 mu = *(const uint4*)(Km + (long)(s0 + s) * D + d0 + c8);
    const u16* kp = (const u16*)&ku;
    const u16* vp = (const u16*)&vu;
    const u16* mp = (const u16*)&mu;
#pragma unroll
    for (int j = 0; j < 8; j++) {
      float p  = __expf(b2f(kp[j]) - b2f(mp[j]));
      float pv = p * b2f(vp[j]);
      lp[s * 66 + c8 + j]  = f2b(p);
      lpv[s * 66 + c8 + j] = f2b(pv);
    }
  }
  __syncthreads();

  const int lane = tid & 63;
  const int wv   = tid >> 6;
#pragma unroll
  for (int it = 0; it < 16; it++) {
    const int d = wv * 16 + it;
    const long oidx = (long)b * TD + (long)(d0 + d) * T + s0 + lane;
    Pt[oidx]  = lp[lane * 66 + d];
    PVt[oidx] = lpv[lane * 66 + d];
  }
}

extern "C" void kernel_launch(void* const* d_in, const int* in_sizes, int n_in,
                              void* d_out, int out_size, void* d_ws, size_t ws_size,
                              hipStream_t stream)
{
  const int B = 32, T = 1024, D = 512;
  const long TD = (long)T * D;
  const void* x    = d_in[0];
  const void* Wk_w = d_in[1];
  const void* Wk_b = d_in[2];
  const void* Wv_w = d_in[3];
  const void* Wv_b = d_in[4];
  const void* Wq_w = d_in[5];
  const void* Wq_b = d_in[6];
  const void* w    = d_in[7];
  const void* Wo_w = d_in[8];
  const void* Wo_b = d_in[9];

  char* ws = (char*)d_ws;
  const size_t MB = 1024 * 1024;
  u16* xb    = (u16*)(ws + 0);          // 32MB [B*T, D]
  u16* Kbuf  = (u16*)(ws + 32 * MB);    // 32MB (aliased as Yt after pexp)
  u16* ewb   = (u16*)(ws + 64 * MB);    // 2MB
  u16* kmb   = (u16*)(ws + 66 * MB);    // 1MB
  u16* Wpack = (u16*)(ws + 67 * MB);    // 1.5MB: Wk;Wv;Wq rows [1536, 512]
  u16* Wvb   = Wpack + 512 * 512;
  u16* Wqb   = Wpack + 2 * 512 * 512;
  u16* Wob   = (u16*)(ws + 68 * MB + 512 * 1024); // 0.5MB
  int* flag  = (int*)(ws + 69 * MB);
  u16* Ytb   = Kbuf;

  dim3 blk(256);

  detect_kernel<<<dim3(1), blk, 0, stream>>>((const u16*)x, flag);
  conv_kernel<<<dim3(8192), blk, 0, stream>>>(x, xb, (long)B * T * D, flag);
  conv4_kernel<<<dim3(512), blk, 0, stream>>>(Wk_w, Wv_w, Wq_w, Wo_w,
                                              Wpack, Wvb, Wqb, Wob, flag);
  expw_kernel<<<dim3(1024), blk, 0, stream>>>(w, ewb, flag);

  if (ws_size >= 200 * MB) {
    // ---- full-batch single-pass path ----
    u16* Vb   = (u16*)(ws + 70 * MB);   // 32MB
    u16* Qb   = (u16*)(ws + 102 * MB);  // 32MB
    u16* Ptb  = (u16*)(ws + 134 * MB);  // 32MB
    u16* PVtb = (u16*)(ws + 166 * MB);  // 32MB -> ends 198MB

    // K,V,Q in one 8-phase GEMM: N = 1536, tile 256x256
    gemm_proj3<<<dim3((B * T) / 256, 6), dim3(512), 0, stream>>>(
        xb, Wpack, Wk_b, Wv_b, Wq_b, Kbuf, Vb, Qb, flag, B * T);

    kmax_kernel<<<dim3(256), blk, 0, stream>>>(Kbuf, kmb);
    pexp_kernel<<<dim3(16, 8, 32), blk, 0, stream>>>(Kbuf, Vb, kmb, Ptb, PVtb);

    // Yt aliases Kbuf (dead after pexp)
    gemm_aft<<<dim3(4, 4, 32), dim3(512), 0, stream>>>(ewb, Ptb, PVtb, Qb, Ytb);

    gemm_out8<<<dim3((B * T) / 256, 2), dim3(512), 0, stream>>>(
        Ytb, Wob, Wo_b, d_out, flag, B * T, D, D);
  } else {
    // ---- chunked fallback (NB=4), 2-phase kernels (known good) ----
    const int NB = 4, NC = B / NB;
    char* ck = ws + 70 * MB;
    const size_t cb = (size_t)NB * TD * sizeof(u16);
    u16* Vc   = (u16*)(ck);
    u16* Ptc  = (u16*)(ck + cb);
    u16* PVtc = (u16*)(ck + 2 * cb);
    u16* Qc   = (u16*)(ck + 3 * cb);
    u16* Ytc  = Vc;

    gemm_bt<0><<<dim3((B * T) / 128, D / 128), blk, 0, stream>>>(
        xb, Wpack, Wk_b, Kbuf, flag, B * T, D, D, 0);
    kmax_kernel<<<dim3(256), blk, 0, stream>>>(Kbuf, kmb);

    dim3 gP((NB * T) / 128, D / 128, 1);
    dim3 gA(4, 4, NB);
    for (int c = 0; c < NC; c++) {
      const long off = (long)c * NB * TD;
      gemm_bt<0><<<gP, blk, 0, stream>>>(xb + off, Wvb, Wv_b, Vc, flag, NB * T, D, D, 0);
      gemm_bt<0><<<gP, blk, 0, stream>>>(xb + off, Wqb, Wq_b, Qc, flag, NB * T, D, D, 0);
      pexp_kernel<<<dim3(16, 8, NB), blk, 0, stream>>>(Kbuf + off, Vc, kmb, Ptc, PVtc);
      gemm_aft<<<gA, dim3(512), 0, stream>>>(ewb, Ptc, PVtc, Qc, Ytc);
      gemm_bt<3><<<gP, blk, 0, stream>>>(Ytc, Wob, Wo_b, d_out, flag, NB * T, D, D, off);
    }
  }
}